// Round 14
// baseline (27.537 us; speedup 1.0000x reference)
//
#include <hip/hip_runtime.h>

#define Bt 32768
#define Dt 64
#define St 16
#define Ht 128
#define At 17

typedef __attribute__((ext_vector_type(8))) short bf16x8;
typedef __attribute__((ext_vector_type(4))) float f32x4;

// ---- workspace layout (bytes) ----
#define CNT_OFF   0          // int[16]
#define PERM_OFF  128        // u16 [S][B]  (1 MiB)
#define WB_OFF    1049600    // bf16 transposed weight images [n][k], XOR-swizzled
#define OA1 0        // Wa1^T: 128 rows x 128B (K=64)
#define OA2 16384    // Wa2^T: 128 rows x 256B (K=128)
#define OA3 49152    // Wa3^T: 32-row region, rows >=17 unused garbage
#define OC1 57344    // Wc1^T
#define OC2 73728    // Wc2^T
#define SKB 106496   // per-skill stride

__device__ __forceinline__ unsigned short f2bf(float f) {
  union { float f; unsigned u; } v; v.f = f;
  unsigned r = v.u + 0x7FFFu + ((v.u >> 16) & 1u);  // RNE
  return (unsigned short)(r >> 16);
}

__device__ __forceinline__ unsigned cvtpk(float a, float b) {
  unsigned r;
  asm("v_cvt_pk_bf16_f32 %0, %1, %2" : "=v"(r) : "v"(a), "v"(b));
  return r;
}

// tanh(acc + bias) with b2 = 2*bias precomputed
__device__ __forceinline__ float tanh_fb(float acc, float b2) {
  const float t = __expf(__builtin_fmaf(acc, 2.0f, b2));  // inf-safe
  const float r = __builtin_amdgcn_rcpf(t + 1.0f);
  return __builtin_fmaf(-2.0f, r, 1.0f);
}

__device__ __forceinline__ f32x4 MFMA(bf16x8 a, bf16x8 b, f32x4 c) {
  return __builtin_amdgcn_mfma_f32_16x16x32_bf16(a, b, c, 0, 0, 0);
}

#define LGKM0() asm volatile("s_waitcnt lgkmcnt(0)" ::: "memory")

__device__ __forceinline__ void ldsload16(const char* g, char* l) {
  __builtin_amdgcn_global_load_lds(
      (const __attribute__((address_space(1))) unsigned int*)g,
      (__attribute__((address_space(3))) unsigned int*)l, 16, 0, 0);
}
__device__ __forceinline__ void stageW(const char* g, char* lds, int bytes,
                                       int wave, int lane) {
  for (int c = wave * 1024; c < bytes; c += 4096)
    ldsload16(g + c + lane * 16, lds + c);
}

// ---------- dispatch 2: prep (blocks 0..111, split K=128) + bucket (112..239, R9) ----------
__global__ __launch_bounds__(256) void k_fused(
    const int* __restrict__ sid, unsigned short* __restrict__ perm,
    int* __restrict__ cnt,
    const float* __restrict__ Wa1, const float* __restrict__ Wa2,
    const float* __restrict__ Wa3, const float* __restrict__ Wc1,
    const float* __restrict__ Wc2, char* __restrict__ G) {
  __shared__ __align__(16) char smem[32768];
  const int tid = threadIdx.x;
  const int bid = blockIdx.x;

  if (bid >= 112) {
    // ---- bucket: R9-proven per-thread LDS atomics, 128 blocks ----
    int* lc = (int*)smem;
    int* lb = lc + St;
    const int b = (bid - 112) * 256 + tid;
    if (tid < St) lc[tid] = 0;
    __syncthreads();
    const int s = sid[b];
    const int p = atomicAdd(&lc[s], 1);
    __syncthreads();
    if (tid < St) lb[tid] = atomicAdd(&cnt[tid], lc[tid]);
    __syncthreads();
    perm[s * Bt + lb[s] + p] = (unsigned short)b;
    return;
  }

  const int s = bid / 7, t = bid % 7;
  char* Gs = G + s * SKB;

  if (t == 3) {  // Wa3: 128x17 -> direct swizzled scatter
    const float* src = Wa3 + s * Ht * At;
    for (int e = tid; e < Ht * At; e += 256) {
      const int k = e / At, n = e - k * At;
      *(unsigned short*)(Gs + OA3 + n * 256 + ((2 * k) ^ ((n & 7) << 4))) =
          f2bf(src[e]);
    }
    return;
  }

  unsigned short* lds = (unsigned short*)smem;
  if (t == 0 || t == 4) {
    // ---- K=64 full matrix (Wa1 / Wc1): 128 rows x 128B ----
    const float* src = (t == 0 ? Wa1 : Wc1) + s * Dt * Ht;
    const int off = (t == 0) ? OA1 : OC1;
    for (int it = 0; it < 8; ++it) {
      const int f = (it * 256 + tid) * 4;
      const int k = f >> 7, n0 = f & 127;
      const f32x4 v = *(const f32x4*)(src + f);
#pragma unroll
      for (int j = 0; j < 4; ++j) {
        const int n = n0 + j;
        const int byte = n * 128 + ((2 * k) ^ (((n >> 2) & 7) << 4));
        lds[byte >> 1] = f2bf(v[j]);
      }
    }
    __syncthreads();
    for (int it = 0; it < 8; ++it) {
      const int q = (it * 256 + tid) * 8;
      const int n = q >> 7, r = q & 127;
      const int srcoff = (r ^ ((n & 7) << 4)) ^ (((n >> 2) & 7) << 4);
      *(unsigned long long*)(Gs + off + q) =
          *(const unsigned long long*)(smem + n * 128 + srcoff);
    }
  } else {
    // ---- K=128 half matrix (Wa2 / Wc2, 64 n-rows per block) ----
    const bool isA = (t <= 2);
    const float* src = (isA ? Wa2 : Wc2) + s * Ht * Ht;
    const int off = isA ? OA2 : OC2;
    const int nhalf = ((t == 2) || (t == 6)) ? 64 : 0;
    for (int it = 0; it < 8; ++it) {
      const int e4 = it * 256 + tid;           // 2048 f32x4 groups
      const int k = e4 >> 4, nl0 = (e4 & 15) * 4;
      const f32x4 v = *(const f32x4*)(src + k * 128 + nhalf + nl0);
#pragma unroll
      for (int j = 0; j < 4; ++j) {
        const int nl = nl0 + j;
        const int byte = nl * 256 + ((2 * k) ^ (((nl >> 2) & 15) << 4));
        lds[byte >> 1] = f2bf(v[j]);
      }
    }
    __syncthreads();
    for (int it = 0; it < 8; ++it) {
      const int q = (it * 256 + tid) * 8;      // 16KB half image
      const int nl = q >> 8, r = q & 255;
      const int srcoff = (r ^ ((nl & 7) << 4)) ^ (((nl >> 2) & 15) << 4);
      *(unsigned long long*)(Gs + off + (nhalf + nl) * 256 + r) =
          *(const unsigned long long*)(smem + nl * 256 + srcoff);
    }
  }
}

__device__ __forceinline__ bf16x8 wrd(const char* base, int srw, int n, int c,
                                      int lg, int msw) {
  return *(const bf16x8*)(base + n * srw + (((c) + lg * 16) ^ msw));
}

// store tanh(acc)+bias with b2 pre-doubled, in registers
__device__ __forceinline__ void storeh(char* hw, int msw, int lg, int t,
                                       const f32x4 acc, const f32x4 b2) {
  const unsigned lo = cvtpk(tanh_fb(acc[0], b2[0]), tanh_fb(acc[1], b2[1]));
  const unsigned hi = cvtpk(tanh_fb(acc[2], b2[2]), tanh_fb(acc[3], b2[3]));
  *(unsigned long long*)(hw + ((32 * t + 8 * lg) ^ msw)) =
      (unsigned long long)lo | ((unsigned long long)hi << 32);
}

// ---- one 64-row tile, actor role (biases in registers) ----
__device__ __forceinline__ void tile_actor(
    int tbase, int rnext, bool dopref, int& rowcur,
    f32x4& cx0, f32x4& cx1, f32x4& cx2, f32x4& cx3,
    const char* wbuf, char* hw, const float* obs,
    const f32x4 (&b1d)[8], const f32x4 (&b2d)[8], const f32x4 ba3v,
    const float ba316, float* out,
    int m, int lg, int msw, int wm, int cs) {
  union { bf16x8 v; unsigned u[4]; } XB0, XB1;
  XB0.u[0] = cvtpk(cx0[0], cx0[1]); XB0.u[1] = cvtpk(cx0[2], cx0[3]);
  XB0.u[2] = cvtpk(cx1[0], cx1[1]); XB0.u[3] = cvtpk(cx1[2], cx1[3]);
  XB1.u[0] = cvtpk(cx2[0], cx2[1]); XB1.u[1] = cvtpk(cx2[2], cx2[3]);
  XB1.u[2] = cvtpk(cx3[0], cx3[1]); XB1.u[3] = cvtpk(cx3[2], cx3[3]);
  const int myrow = rowcur;
  if (dopref) {  // next tile's obs: in flight across this tile's compute
    const float* ap = obs + rnext * Dt + lg * 8;
    cx0 = *(const f32x4*)(ap);      cx1 = *(const f32x4*)(ap + 4);
    cx2 = *(const f32x4*)(ap + 32); cx3 = *(const f32x4*)(ap + 36);
  }
  rowcur = rnext;
#pragma unroll
  for (int nt = 0; nt < 8; ++nt) {
    const bf16x8 a0 = wrd(wbuf, 128, nt * 16 + m, 0, lg, msw);
    const bf16x8 a1 = wrd(wbuf, 128, nt * 16 + m, 64, lg, msw);
    f32x4 acc = {0.f, 0.f, 0.f, 0.f};
    acc = MFMA(a0, XB0.v, acc);
    acc = MFMA(a1, XB1.v, acc);
    storeh(hw, msw, lg, nt, acc, b1d[nt]);
  }
  LGKM0();
  const bf16x8 h0 = *(const bf16x8*)(hw + ((0   + 16 * lg) ^ msw));
  const bf16x8 h1 = *(const bf16x8*)(hw + ((64  + 16 * lg) ^ msw));
  const bf16x8 h2 = *(const bf16x8*)(hw + ((128 + 16 * lg) ^ msw));
  const bf16x8 h3 = *(const bf16x8*)(hw + ((192 + 16 * lg) ^ msw));
#pragma unroll
  for (int nt = 0; nt < 8; ++nt) {
    const int n = nt * 16 + m;
    const bf16x8 w0 = wrd(wbuf + 16384, 256, n, 0, lg, msw);
    const bf16x8 w1 = wrd(wbuf + 16384, 256, n, 64, lg, msw);
    const bf16x8 w2 = wrd(wbuf + 16384, 256, n, 128, lg, msw);
    const bf16x8 w3 = wrd(wbuf + 16384, 256, n, 192, lg, msw);
    f32x4 acc = {0.f, 0.f, 0.f, 0.f};
    acc = MFMA(w0, h0, acc); acc = MFMA(w1, h1, acc);
    acc = MFMA(w2, h2, acc); acc = MFMA(w3, h3, acc);
    storeh(hw, msw, lg, nt, acc, b2d[nt]);
  }
  LGKM0();
  const bf16x8 H0 = *(const bf16x8*)(hw + ((0   + 16 * lg) ^ msw));
  const bf16x8 H1 = *(const bf16x8*)(hw + ((64  + 16 * lg) ^ msw));
  const bf16x8 H2 = *(const bf16x8*)(hw + ((128 + 16 * lg) ^ msw));
  const bf16x8 H3 = *(const bf16x8*)(hw + ((192 + 16 * lg) ^ msw));
  const char* W3 = wbuf + 49152;
  const bf16x8 e0 = wrd(W3, 256, m, 0, lg, msw);
  const bf16x8 e1 = wrd(W3, 256, m, 64, lg, msw);
  const bf16x8 e2 = wrd(W3, 256, m, 128, lg, msw);
  const bf16x8 e3 = wrd(W3, 256, m, 192, lg, msw);
  const bf16x8 f0 = wrd(W3, 256, 16 + m, 0, lg, msw);
  const bf16x8 f1 = wrd(W3, 256, 16 + m, 64, lg, msw);
  const bf16x8 f2 = wrd(W3, 256, 16 + m, 128, lg, msw);
  const bf16x8 f3 = wrd(W3, 256, 16 + m, 192, lg, msw);
  f32x4 p0 = {0.f, 0.f, 0.f, 0.f}, p1 = {0.f, 0.f, 0.f, 0.f};
  p0 = MFMA(e0, H0, p0); p0 = MFMA(e1, H1, p0);
  p0 = MFMA(e2, H2, p0); p0 = MFMA(e3, H3, p0);
  p1 = MFMA(f0, H0, p1); p1 = MFMA(f1, H1, p1);
  p1 = MFMA(f2, H2, p1); p1 = MFMA(f3, H3, p1);
  if (tbase + wm < cs) {
    float* orow = out + myrow * At;
#pragma unroll
    for (int i = 0; i < 4; ++i)                 // n = 4lg+i in 0..15
      orow[4 * lg + i] = p0[i] + ba3v[i];
    if (lg == 0) orow[16] = p1[0] + ba316;      // n = 16
  }
}

// ---- one 64-row tile, critic role (biases/Wc3 in registers) ----
__device__ __forceinline__ void tile_critic(
    int tbase, int rnext, bool dopref, int& rowcur,
    f32x4& cx0, f32x4& cx1, f32x4& cx2, f32x4& cx3,
    const char* wbuf, char* hw, const float* obs,
    const f32x4 (&b1d)[8], const f32x4 (&b2d)[8], const f32x4 (&wv)[8],
    const float bc3s, float* out,
    int m, int lg, int msw, int wm, int cs, int lane) {
  union { bf16x8 v; unsigned u[4]; } XB0, XB1;
  XB0.u[0] = cvtpk(cx0[0], cx0[1]); XB0.u[1] = cvtpk(cx0[2], cx0[3]);
  XB0.u[2] = cvtpk(cx1[0], cx1[1]); XB0.u[3] = cvtpk(cx1[2], cx1[3]);
  XB1.u[0] = cvtpk(cx2[0], cx2[1]); XB1.u[1] = cvtpk(cx2[2], cx2[3]);
  XB1.u[2] = cvtpk(cx3[0], cx3[1]); XB1.u[3] = cvtpk(cx3[2], cx3[3]);
  const int myrow = rowcur;
  if (dopref) {
    const float* ap = obs + rnext * Dt + lg * 8;
    cx0 = *(const f32x4*)(ap);      cx1 = *(const f32x4*)(ap + 4);
    cx2 = *(const f32x4*)(ap + 32); cx3 = *(const f32x4*)(ap + 36);
  }
  rowcur = rnext;
#pragma unroll
  for (int nt = 0; nt < 8; ++nt) {
    const bf16x8 a0 = wrd(wbuf, 128, nt * 16 + m, 0, lg, msw);
    const bf16x8 a1 = wrd(wbuf, 128, nt * 16 + m, 64, lg, msw);
    f32x4 acc = {0.f, 0.f, 0.f, 0.f};
    acc = MFMA(a0, XB0.v, acc);
    acc = MFMA(a1, XB1.v, acc);
    storeh(hw, msw, lg, nt, acc, b1d[nt]);
  }
  LGKM0();
  const bf16x8 h0 = *(const bf16x8*)(hw + ((0   + 16 * lg) ^ msw));
  const bf16x8 h1 = *(const bf16x8*)(hw + ((64  + 16 * lg) ^ msw));
  const bf16x8 h2 = *(const bf16x8*)(hw + ((128 + 16 * lg) ^ msw));
  const bf16x8 h3 = *(const bf16x8*)(hw + ((192 + 16 * lg) ^ msw));
  float vp = 0.f;
#pragma unroll
  for (int nt = 0; nt < 8; ++nt) {
    const int n = nt * 16 + m;
    const bf16x8 w0 = wrd(wbuf + 16384, 256, n, 0, lg, msw);
    const bf16x8 w1 = wrd(wbuf + 16384, 256, n, 64, lg, msw);
    const bf16x8 w2 = wrd(wbuf + 16384, 256, n, 128, lg, msw);
    const bf16x8 w3 = wrd(wbuf + 16384, 256, n, 192, lg, msw);
    f32x4 acc = {0.f, 0.f, 0.f, 0.f};
    acc = MFMA(w0, h0, acc); acc = MFMA(w1, h1, acc);
    acc = MFMA(w2, h2, acc); acc = MFMA(w3, h3, acc);
#pragma unroll
    for (int i = 0; i < 4; ++i)
      vp = __builtin_fmaf(tanh_fb(acc[i], b2d[nt][i]), wv[nt][i], vp);
  }
  vp += __shfl_xor(vp, 16);
  vp += __shfl_xor(vp, 32);
  if (lane < 16 && (tbase + wm < cs)) out[Bt * At + myrow] = vp + bc3s;
}

// ---------- dispatch 3: persistent per-(skill,role) blocks; role = SLOWEST grid dim ----------
// linear id(actor pair) and id(critic pair) differ by exactly 256 = 8 XCDs x 32 CUs:
// under round-robin dispatch both land on the same CU -> shared obs rows hit L1,
// and the short critic block drains early while the long actor block fills the CU.
__global__ __launch_bounds__(256, 2) void k_main(
    const float* __restrict__ obs,
    const float* __restrict__ ba1, const float* __restrict__ ba2,
    const float* __restrict__ ba3, const float* __restrict__ bc1,
    const float* __restrict__ bc2, const float* __restrict__ Wc3,
    const float* __restrict__ bc3,
    const int* __restrict__ cnt, const unsigned short* __restrict__ perm,
    const char* __restrict__ G, float* __restrict__ out) {
  __shared__ __align__(16) char wbuf[57344];  // L1@0 16K | L2@16K 32K | L3@48K 8K
  __shared__ __align__(16) char hbuf[16384];  // 64 rows x 256B, wave-private rows

  const int tid = threadIdx.x;
  const int wave = tid >> 6, lane = tid & 63;
  const int m = lane & 15, lg = lane >> 4;
  const bool actor = (blockIdx.z == 0);       // role slowest
  const int s = blockIdx.x, idx = blockIdx.y;
  const char* Gs = G + s * SKB;
  const int wm = wave * 16 + m;

  // perm for this block's (up to 3) tiles: no cnt dependency -> issue first
  const unsigned short* pb = perm + s * Bt;
  int r0 = pb[idx * 64 + wm];
  int r1 = pb[(idx + 16) * 64 + wm];
  int r2 = pb[(idx + 32) * 64 + wm];
  const int cs = cnt[s];

  // stage all weights ONCE
  if (actor) {
    stageW(Gs + OA1, wbuf, 16384, wave, lane);
    stageW(Gs + OA2, wbuf + 16384, 32768, wave, lane);
    stageW(Gs + OA3, wbuf + 49152, 8192, wave, lane);
  } else {
    stageW(Gs + OC1, wbuf, 16384, wave, lane);
    stageW(Gs + OC2, wbuf + 16384, 32768, wave, lane);
  }

  r0 = min(r0, Bt - 1); r1 = min(r1, Bt - 1); r2 = min(r2, Bt - 1);
  const int ntl = (cs + 63) >> 6;

  f32x4 cx0, cx1, cx2, cx3;
  {
    const float* ap = obs + r0 * Dt + lg * 8;
    cx0 = *(const f32x4*)(ap);      cx1 = *(const f32x4*)(ap + 4);
    cx2 = *(const f32x4*)(ap + 32); cx3 = *(const f32x4*)(ap + 36);
  }

  char* hw = hbuf + wm * 256;
  const int msw = (m & 7) << 4;
  int rowcur = r0;

  if (actor) {
    // preload all biases into registers (pre-doubled) BEFORE the barrier
    f32x4 b1d[8], b2d[8];
#pragma unroll
    for (int nt = 0; nt < 8; ++nt) {
      const f32x4 t1 = *(const f32x4*)(ba1 + s * Ht + nt * 16 + lg * 4);
      const f32x4 t2 = *(const f32x4*)(ba2 + s * Ht + nt * 16 + lg * 4);
      b1d[nt] = t1 + t1;
      b2d[nt] = t2 + t2;
    }
    const f32x4 ba3v = *(const f32x4*)(ba3 + s * At + 4 * lg);
    const float ba316 = ba3[s * At + 16];
    __syncthreads();                     // weights + all reg preloads drained
    tile_actor(idx * 64, r1, true, rowcur, cx0, cx1, cx2, cx3,
               wbuf, hw, obs, b1d, b2d, ba3v, ba316, out, m, lg, msw, wm, cs);
    if (idx + 16 < ntl)
      tile_actor((idx + 16) * 64, r2, true, rowcur, cx0, cx1, cx2, cx3,
                 wbuf, hw, obs, b1d, b2d, ba3v, ba316, out, m, lg, msw, wm, cs);
    if (idx + 32 < ntl)
      tile_actor((idx + 32) * 64, r2, false, rowcur, cx0, cx1, cx2, cx3,
                 wbuf, hw, obs, b1d, b2d, ba3v, ba316, out, m, lg, msw, wm, cs);
  } else {
    f32x4 b1d[8], b2d[8], wv[8];
#pragma unroll
    for (int nt = 0; nt < 8; ++nt) {
      const f32x4 t1 = *(const f32x4*)(bc1 + s * Ht + nt * 16 + lg * 4);
      const f32x4 t2 = *(const f32x4*)(bc2 + s * Ht + nt * 16 + lg * 4);
      wv[nt] = *(const f32x4*)(Wc3 + s * Ht + nt * 16 + lg * 4);
      b1d[nt] = t1 + t1;
      b2d[nt] = t2 + t2;
    }
    const float bc3s = bc3[s];
    __syncthreads();
    tile_critic(idx * 64, r1, true, rowcur, cx0, cx1, cx2, cx3,
                wbuf, hw, obs, b1d, b2d, wv, bc3s, out, m, lg, msw, wm, cs, lane);
    if (idx + 16 < ntl)
      tile_critic((idx + 16) * 64, r2, true, rowcur, cx0, cx1, cx2, cx3,
                  wbuf, hw, obs, b1d, b2d, wv, bc3s, out, m, lg, msw, wm, cs, lane);
    if (idx + 32 < ntl)
      tile_critic((idx + 32) * 64, r2, false, rowcur, cx0, cx1, cx2, cx3,
                  wbuf, hw, obs, b1d, b2d, wv, bc3s, out, m, lg, msw, wm, cs, lane);
  }
}

extern "C" void kernel_launch(void* const* d_in, const int* in_sizes, int n_in,
                              void* d_out, int out_size, void* d_ws, size_t ws_size,
                              hipStream_t stream) {
  const float* obs = (const float*)d_in[0];
  const int* sid   = (const int*)d_in[1];
  const float* Wa1 = (const float*)d_in[2];
  const float* ba1 = (const float*)d_in[3];
  const float* Wa2 = (const float*)d_in[4];
  const float* ba2 = (const float*)d_in[5];
  const float* Wa3 = (const float*)d_in[6];
  const float* ba3 = (const float*)d_in[7];
  const float* Wc1 = (const float*)d_in[8];
  const float* bc1 = (const float*)d_in[9];
  const float* Wc2 = (const float*)d_in[10];
  const float* bc2 = (const float*)d_in[11];
  const float* Wc3 = (const float*)d_in[12];
  const float* bc3 = (const float*)d_in[13];
  float* out = (float*)d_out;
  char* ws = (char*)d_ws;

  int* cnt = (int*)(ws + CNT_OFF);
  unsigned short* perm = (unsigned short*)(ws + PERM_OFF);
  char* G = ws + WB_OFF;

  hipMemsetAsync(cnt, 0, St * sizeof(int), stream);
  k_fused<<<dim3(240), dim3(256), 0, stream>>>(sid, perm, cnt, Wa1, Wa2, Wa3, Wc1, Wc2, G);
  k_main<<<dim3(16, 16, 2), dim3(256), 0, stream>>>(
      obs, ba1, ba2, ba3, bc1, bc2, Wc3, bc3, cnt, perm, G, out);
}

// Round 15
// 26.285 us; speedup vs baseline: 1.0476x; 1.0476x over previous
//
#include <hip/hip_runtime.h>

#define Bt 32768
#define Dt 64
#define St 16
#define Ht 128
#define At 17

typedef __attribute__((ext_vector_type(8))) short bf16x8;
typedef __attribute__((ext_vector_type(4))) float f32x4;

// ---- workspace layout (bytes) ----
#define CNT_OFF   0          // int[16]
#define PERM_OFF  128        // u16 [S][B]  (1 MiB)
#define WB_OFF    1049600    // bf16 transposed weight images [n][k], XOR-swizzled
#define OA1 0        // Wa1^T: 128 rows x 128B (K=64)
#define OA2 16384    // Wa2^T: 128 rows x 256B (K=128)
#define OA3 49152    // Wa3^T: 32-row region, rows >=17 unused garbage
#define OC1 57344    // Wc1^T
#define OC2 73728    // Wc2^T
#define SKB 106496   // per-skill stride

__device__ __forceinline__ unsigned short f2bf(float f) {
  union { float f; unsigned u; } v; v.f = f;
  unsigned r = v.u + 0x7FFFu + ((v.u >> 16) & 1u);  // RNE
  return (unsigned short)(r >> 16);
}

__device__ __forceinline__ unsigned cvtpk(float a, float b) {
  unsigned r;
  asm("v_cvt_pk_bf16_f32 %0, %1, %2" : "=v"(r) : "v"(a), "v"(b));
  return r;
}

// tanh(acc + bias) with b2 = 2*bias precomputed
__device__ __forceinline__ float tanh_fb(float acc, float b2) {
  const float t = __expf(__builtin_fmaf(acc, 2.0f, b2));  // inf-safe
  const float r = __builtin_amdgcn_rcpf(t + 1.0f);
  return __builtin_fmaf(-2.0f, r, 1.0f);
}

__device__ __forceinline__ f32x4 MFMA(bf16x8 a, bf16x8 b, f32x4 c) {
  return __builtin_amdgcn_mfma_f32_16x16x32_bf16(a, b, c, 0, 0, 0);
}

#define LGKM0() asm volatile("s_waitcnt lgkmcnt(0)" ::: "memory")
#define PRIO1() __builtin_amdgcn_s_setprio(1)
#define PRIO0() __builtin_amdgcn_s_setprio(0)

__device__ __forceinline__ void ldsload16(const char* g, char* l) {
  __builtin_amdgcn_global_load_lds(
      (const __attribute__((address_space(1))) unsigned int*)g,
      (__attribute__((address_space(3))) unsigned int*)l, 16, 0, 0);
}
__device__ __forceinline__ void stageW(const char* g, char* lds, int bytes,
                                       int wave, int lane) {
  for (int c = wave * 1024; c < bytes; c += 4096)
    ldsload16(g + c + lane * 16, lds + c);
}

// ---------- dispatch 2: prep (blocks 0..111, split K=128) + bucket (112..239, R9) ----------
__global__ __launch_bounds__(256) void k_fused(
    const int* __restrict__ sid, unsigned short* __restrict__ perm,
    int* __restrict__ cnt,
    const float* __restrict__ Wa1, const float* __restrict__ Wa2,
    const float* __restrict__ Wa3, const float* __restrict__ Wc1,
    const float* __restrict__ Wc2, char* __restrict__ G) {
  __shared__ __align__(16) char smem[32768];
  const int tid = threadIdx.x;
  const int bid = blockIdx.x;

  if (bid >= 112) {
    // ---- bucket: R9-proven per-thread LDS atomics, 128 blocks ----
    int* lc = (int*)smem;
    int* lb = lc + St;
    const int b = (bid - 112) * 256 + tid;
    if (tid < St) lc[tid] = 0;
    __syncthreads();
    const int s = sid[b];
    const int p = atomicAdd(&lc[s], 1);
    __syncthreads();
    if (tid < St) lb[tid] = atomicAdd(&cnt[tid], lc[tid]);
    __syncthreads();
    perm[s * Bt + lb[s] + p] = (unsigned short)b;
    return;
  }

  const int s = bid / 7, t = bid % 7;
  char* Gs = G + s * SKB;

  if (t == 3) {  // Wa3: 128x17 -> direct swizzled scatter
    const float* src = Wa3 + s * Ht * At;
    for (int e = tid; e < Ht * At; e += 256) {
      const int k = e / At, n = e - k * At;
      *(unsigned short*)(Gs + OA3 + n * 256 + ((2 * k) ^ ((n & 7) << 4))) =
          f2bf(src[e]);
    }
    return;
  }

  unsigned short* lds = (unsigned short*)smem;
  if (t == 0 || t == 4) {
    // ---- K=64 full matrix (Wa1 / Wc1): 128 rows x 128B ----
    const float* src = (t == 0 ? Wa1 : Wc1) + s * Dt * Ht;
    const int off = (t == 0) ? OA1 : OC1;
    for (int it = 0; it < 8; ++it) {
      const int f = (it * 256 + tid) * 4;
      const int k = f >> 7, n0 = f & 127;
      const f32x4 v = *(const f32x4*)(src + f);
#pragma unroll
      for (int j = 0; j < 4; ++j) {
        const int n = n0 + j;
        const int byte = n * 128 + ((2 * k) ^ (((n >> 2) & 7) << 4));
        lds[byte >> 1] = f2bf(v[j]);
      }
    }
    __syncthreads();
    for (int it = 0; it < 8; ++it) {
      const int q = (it * 256 + tid) * 8;
      const int n = q >> 7, r = q & 127;
      const int srcoff = (r ^ ((n & 7) << 4)) ^ (((n >> 2) & 7) << 4);
      *(unsigned long long*)(Gs + off + q) =
          *(const unsigned long long*)(smem + n * 128 + srcoff);
    }
  } else {
    // ---- K=128 half matrix (Wa2 / Wc2, 64 n-rows per block) ----
    const bool isA = (t <= 2);
    const float* src = (isA ? Wa2 : Wc2) + s * Ht * Ht;
    const int off = isA ? OA2 : OC2;
    const int nhalf = ((t == 2) || (t == 6)) ? 64 : 0;
    for (int it = 0; it < 8; ++it) {
      const int e4 = it * 256 + tid;           // 2048 f32x4 groups
      const int k = e4 >> 4, nl0 = (e4 & 15) * 4;
      const f32x4 v = *(const f32x4*)(src + k * 128 + nhalf + nl0);
#pragma unroll
      for (int j = 0; j < 4; ++j) {
        const int nl = nl0 + j;
        const int byte = nl * 256 + ((2 * k) ^ (((nl >> 2) & 15) << 4));
        lds[byte >> 1] = f2bf(v[j]);
      }
    }
    __syncthreads();
    for (int it = 0; it < 8; ++it) {
      const int q = (it * 256 + tid) * 8;      // 16KB half image
      const int nl = q >> 8, r = q & 255;
      const int srcoff = (r ^ ((nl & 7) << 4)) ^ (((nl >> 2) & 15) << 4);
      *(unsigned long long*)(Gs + off + (nhalf + nl) * 256 + r) =
          *(const unsigned long long*)(smem + nl * 256 + srcoff);
    }
  }
}

__device__ __forceinline__ bf16x8 wrd(const char* base, int srw, int n, int c,
                                      int lg, int msw) {
  return *(const bf16x8*)(base + n * srw + (((c) + lg * 16) ^ msw));
}

// store tanh(acc)+bias with b2 pre-doubled, in registers
__device__ __forceinline__ void storeh(char* hw, int msw, int lg, int t,
                                       const f32x4 acc, const f32x4 b2) {
  const unsigned lo = cvtpk(tanh_fb(acc[0], b2[0]), tanh_fb(acc[1], b2[1]));
  const unsigned hi = cvtpk(tanh_fb(acc[2], b2[2]), tanh_fb(acc[3], b2[3]));
  *(unsigned long long*)(hw + ((32 * t + 8 * lg) ^ msw)) =
      (unsigned long long)lo | ((unsigned long long)hi << 32);
}

// ---- one 64-row tile, actor role (biases in registers) ----
__device__ __forceinline__ void tile_actor(
    int tbase, int rnext, bool dopref, int& rowcur,
    f32x4& cx0, f32x4& cx1, f32x4& cx2, f32x4& cx3,
    const char* wbuf, char* hw, const float* obs,
    const f32x4 (&b1d)[8], const f32x4 (&b2d)[8], const f32x4 ba3v,
    const float ba316, float* out,
    int m, int lg, int msw, int wm, int cs) {
  union { bf16x8 v; unsigned u[4]; } XB0, XB1;
  XB0.u[0] = cvtpk(cx0[0], cx0[1]); XB0.u[1] = cvtpk(cx0[2], cx0[3]);
  XB0.u[2] = cvtpk(cx1[0], cx1[1]); XB0.u[3] = cvtpk(cx1[2], cx1[3]);
  XB1.u[0] = cvtpk(cx2[0], cx2[1]); XB1.u[1] = cvtpk(cx2[2], cx2[3]);
  XB1.u[2] = cvtpk(cx3[0], cx3[1]); XB1.u[3] = cvtpk(cx3[2], cx3[3]);
  const int myrow = rowcur;
  if (dopref) {  // next tile's obs: in flight across this tile's compute
    const float* ap = obs + rnext * Dt + lg * 8;
    cx0 = *(const f32x4*)(ap);      cx1 = *(const f32x4*)(ap + 4);
    cx2 = *(const f32x4*)(ap + 32); cx3 = *(const f32x4*)(ap + 36);
  }
  rowcur = rnext;
#pragma unroll
  for (int nt = 0; nt < 8; ++nt) {
    const bf16x8 a0 = wrd(wbuf, 128, nt * 16 + m, 0, lg, msw);
    const bf16x8 a1 = wrd(wbuf, 128, nt * 16 + m, 64, lg, msw);
    f32x4 acc = {0.f, 0.f, 0.f, 0.f};
    PRIO1();
    acc = MFMA(a0, XB0.v, acc);
    acc = MFMA(a1, XB1.v, acc);
    PRIO0();
    storeh(hw, msw, lg, nt, acc, b1d[nt]);
  }
  LGKM0();
  const bf16x8 h0 = *(const bf16x8*)(hw + ((0   + 16 * lg) ^ msw));
  const bf16x8 h1 = *(const bf16x8*)(hw + ((64  + 16 * lg) ^ msw));
  const bf16x8 h2 = *(const bf16x8*)(hw + ((128 + 16 * lg) ^ msw));
  const bf16x8 h3 = *(const bf16x8*)(hw + ((192 + 16 * lg) ^ msw));
#pragma unroll
  for (int nt = 0; nt < 8; ++nt) {
    const int n = nt * 16 + m;
    const bf16x8 w0 = wrd(wbuf + 16384, 256, n, 0, lg, msw);
    const bf16x8 w1 = wrd(wbuf + 16384, 256, n, 64, lg, msw);
    const bf16x8 w2 = wrd(wbuf + 16384, 256, n, 128, lg, msw);
    const bf16x8 w3 = wrd(wbuf + 16384, 256, n, 192, lg, msw);
    f32x4 acc = {0.f, 0.f, 0.f, 0.f};
    PRIO1();
    acc = MFMA(w0, h0, acc); acc = MFMA(w1, h1, acc);
    acc = MFMA(w2, h2, acc); acc = MFMA(w3, h3, acc);
    PRIO0();
    storeh(hw, msw, lg, nt, acc, b2d[nt]);
  }
  LGKM0();
  const bf16x8 H0 = *(const bf16x8*)(hw + ((0   + 16 * lg) ^ msw));
  const bf16x8 H1 = *(const bf16x8*)(hw + ((64  + 16 * lg) ^ msw));
  const bf16x8 H2 = *(const bf16x8*)(hw + ((128 + 16 * lg) ^ msw));
  const bf16x8 H3 = *(const bf16x8*)(hw + ((192 + 16 * lg) ^ msw));
  const char* W3 = wbuf + 49152;
  const bf16x8 e0 = wrd(W3, 256, m, 0, lg, msw);
  const bf16x8 e1 = wrd(W3, 256, m, 64, lg, msw);
  const bf16x8 e2 = wrd(W3, 256, m, 128, lg, msw);
  const bf16x8 e3 = wrd(W3, 256, m, 192, lg, msw);
  const bf16x8 f0 = wrd(W3, 256, 16 + m, 0, lg, msw);
  const bf16x8 f1 = wrd(W3, 256, 16 + m, 64, lg, msw);
  const bf16x8 f2 = wrd(W3, 256, 16 + m, 128, lg, msw);
  const bf16x8 f3 = wrd(W3, 256, 16 + m, 192, lg, msw);
  f32x4 p0 = {0.f, 0.f, 0.f, 0.f}, p1 = {0.f, 0.f, 0.f, 0.f};
  PRIO1();
  p0 = MFMA(e0, H0, p0); p0 = MFMA(e1, H1, p0);
  p0 = MFMA(e2, H2, p0); p0 = MFMA(e3, H3, p0);
  p1 = MFMA(f0, H0, p1); p1 = MFMA(f1, H1, p1);
  p1 = MFMA(f2, H2, p1); p1 = MFMA(f3, H3, p1);
  PRIO0();
  if (tbase + wm < cs) {
    float* orow = out + myrow * At;
#pragma unroll
    for (int i = 0; i < 4; ++i)                 // n = 4lg+i in 0..15
      orow[4 * lg + i] = p0[i] + ba3v[i];
    if (lg == 0) orow[16] = p1[0] + ba316;      // n = 16
  }
}

// ---- one 64-row tile, critic role (biases/Wc3 in registers) ----
__device__ __forceinline__ void tile_critic(
    int tbase, int rnext, bool dopref, int& rowcur,
    f32x4& cx0, f32x4& cx1, f32x4& cx2, f32x4& cx3,
    const char* wbuf, char* hw, const float* obs,
    const f32x4 (&b1d)[8], const f32x4 (&b2d)[8], const f32x4 (&wv)[8],
    const float bc3s, float* out,
    int m, int lg, int msw, int wm, int cs, int lane) {
  union { bf16x8 v; unsigned u[4]; } XB0, XB1;
  XB0.u[0] = cvtpk(cx0[0], cx0[1]); XB0.u[1] = cvtpk(cx0[2], cx0[3]);
  XB0.u[2] = cvtpk(cx1[0], cx1[1]); XB0.u[3] = cvtpk(cx1[2], cx1[3]);
  XB1.u[0] = cvtpk(cx2[0], cx2[1]); XB1.u[1] = cvtpk(cx2[2], cx2[3]);
  XB1.u[2] = cvtpk(cx3[0], cx3[1]); XB1.u[3] = cvtpk(cx3[2], cx3[3]);
  const int myrow = rowcur;
  if (dopref) {
    const float* ap = obs + rnext * Dt + lg * 8;
    cx0 = *(const f32x4*)(ap);      cx1 = *(const f32x4*)(ap + 4);
    cx2 = *(const f32x4*)(ap + 32); cx3 = *(const f32x4*)(ap + 36);
  }
  rowcur = rnext;
#pragma unroll
  for (int nt = 0; nt < 8; ++nt) {
    const bf16x8 a0 = wrd(wbuf, 128, nt * 16 + m, 0, lg, msw);
    const bf16x8 a1 = wrd(wbuf, 128, nt * 16 + m, 64, lg, msw);
    f32x4 acc = {0.f, 0.f, 0.f, 0.f};
    PRIO1();
    acc = MFMA(a0, XB0.v, acc);
    acc = MFMA(a1, XB1.v, acc);
    PRIO0();
    storeh(hw, msw, lg, nt, acc, b1d[nt]);
  }
  LGKM0();
  const bf16x8 h0 = *(const bf16x8*)(hw + ((0   + 16 * lg) ^ msw));
  const bf16x8 h1 = *(const bf16x8*)(hw + ((64  + 16 * lg) ^ msw));
  const bf16x8 h2 = *(const bf16x8*)(hw + ((128 + 16 * lg) ^ msw));
  const bf16x8 h3 = *(const bf16x8*)(hw + ((192 + 16 * lg) ^ msw));
  float vp = 0.f;
#pragma unroll
  for (int nt = 0; nt < 8; ++nt) {
    const int n = nt * 16 + m;
    const bf16x8 w0 = wrd(wbuf + 16384, 256, n, 0, lg, msw);
    const bf16x8 w1 = wrd(wbuf + 16384, 256, n, 64, lg, msw);
    const bf16x8 w2 = wrd(wbuf + 16384, 256, n, 128, lg, msw);
    const bf16x8 w3 = wrd(wbuf + 16384, 256, n, 192, lg, msw);
    f32x4 acc = {0.f, 0.f, 0.f, 0.f};
    PRIO1();
    acc = MFMA(w0, h0, acc); acc = MFMA(w1, h1, acc);
    acc = MFMA(w2, h2, acc); acc = MFMA(w3, h3, acc);
    PRIO0();
#pragma unroll
    for (int i = 0; i < 4; ++i)
      vp = __builtin_fmaf(tanh_fb(acc[i], b2d[nt][i]), wv[nt][i], vp);
  }
  vp += __shfl_xor(vp, 16);
  vp += __shfl_xor(vp, 32);
  if (lane < 16 && (tbase + wm < cs)) out[Bt * At + myrow] = vp + bc3s;
}

// ---------- dispatch 3: persistent per-(skill,role) blocks; staged once (R12) ----------
// grid (role, s, idx) role-fastest: co-resident blocks (id, id+256) share (role,s)
// -> second block's weight stage hits warm L2 (R14 confirmed this by regressing).
__global__ __launch_bounds__(256, 2) void k_main(
    const float* __restrict__ obs,
    const float* __restrict__ ba1, const float* __restrict__ ba2,
    const float* __restrict__ ba3, const float* __restrict__ bc1,
    const float* __restrict__ bc2, const float* __restrict__ Wc3,
    const float* __restrict__ bc3,
    const int* __restrict__ cnt, const unsigned short* __restrict__ perm,
    const char* __restrict__ G, float* __restrict__ out) {
  __shared__ __align__(16) char wbuf[57344];  // L1@0 16K | L2@16K 32K | L3@48K 8K
  __shared__ __align__(16) char hbuf[16384];  // 64 rows x 256B, wave-private rows

  const int tid = threadIdx.x;
  const int wave = tid >> 6, lane = tid & 63;
  const int m = lane & 15, lg = lane >> 4;
  const bool actor = (blockIdx.x == 0);
  const int s = blockIdx.y, idx = blockIdx.z;
  const char* Gs = G + s * SKB;
  const int wm = wave * 16 + m;

  // perm for this block's (up to 3) tiles: no cnt dependency -> issue first
  const unsigned short* pb = perm + s * Bt;
  int r0 = pb[idx * 64 + wm];
  int r1 = pb[(idx + 16) * 64 + wm];
  int r2 = pb[(idx + 32) * 64 + wm];
  const int cs = cnt[s];

  // stage all weights ONCE
  if (actor) {
    stageW(Gs + OA1, wbuf, 16384, wave, lane);
    stageW(Gs + OA2, wbuf + 16384, 32768, wave, lane);
    stageW(Gs + OA3, wbuf + 49152, 8192, wave, lane);
  } else {
    stageW(Gs + OC1, wbuf, 16384, wave, lane);
    stageW(Gs + OC2, wbuf + 16384, 32768, wave, lane);
  }

  r0 = min(r0, Bt - 1); r1 = min(r1, Bt - 1); r2 = min(r2, Bt - 1);
  const int ntl = (cs + 63) >> 6;

  f32x4 cx0, cx1, cx2, cx3;
  {
    const float* ap = obs + r0 * Dt + lg * 8;
    cx0 = *(const f32x4*)(ap);      cx1 = *(const f32x4*)(ap + 4);
    cx2 = *(const f32x4*)(ap + 32); cx3 = *(const f32x4*)(ap + 36);
  }

  char* hw = hbuf + wm * 256;
  const int msw = (m & 7) << 4;
  int rowcur = r0;

  if (actor) {
    // preload all biases into registers (pre-doubled) BEFORE the barrier
    f32x4 b1d[8], b2d[8];
#pragma unroll
    for (int nt = 0; nt < 8; ++nt) {
      const f32x4 t1 = *(const f32x4*)(ba1 + s * Ht + nt * 16 + lg * 4);
      const f32x4 t2 = *(const f32x4*)(ba2 + s * Ht + nt * 16 + lg * 4);
      b1d[nt] = t1 + t1;
      b2d[nt] = t2 + t2;
    }
    const f32x4 ba3v = *(const f32x4*)(ba3 + s * At + 4 * lg);
    const float ba316 = ba3[s * At + 16];
    __syncthreads();                     // weights + all reg preloads drained
    tile_actor(idx * 64, r1, true, rowcur, cx0, cx1, cx2, cx3,
               wbuf, hw, obs, b1d, b2d, ba3v, ba316, out, m, lg, msw, wm, cs);
    if (idx + 16 < ntl)
      tile_actor((idx + 16) * 64, r2, true, rowcur, cx0, cx1, cx2, cx3,
                 wbuf, hw, obs, b1d, b2d, ba3v, ba316, out, m, lg, msw, wm, cs);
    if (idx + 32 < ntl)
      tile_actor((idx + 32) * 64, r2, false, rowcur, cx0, cx1, cx2, cx3,
                 wbuf, hw, obs, b1d, b2d, ba3v, ba316, out, m, lg, msw, wm, cs);
  } else {
    f32x4 b1d[8], b2d[8], wv[8];
#pragma unroll
    for (int nt = 0; nt < 8; ++nt) {
      const f32x4 t1 = *(const f32x4*)(bc1 + s * Ht + nt * 16 + lg * 4);
      const f32x4 t2 = *(const f32x4*)(bc2 + s * Ht + nt * 16 + lg * 4);
      wv[nt] = *(const f32x4*)(Wc3 + s * Ht + nt * 16 + lg * 4);
      b1d[nt] = t1 + t1;
      b2d[nt] = t2 + t2;
    }
    const float bc3s = bc3[s];
    __syncthreads();
    tile_critic(idx * 64, r1, true, rowcur, cx0, cx1, cx2, cx3,
                wbuf, hw, obs, b1d, b2d, wv, bc3s, out, m, lg, msw, wm, cs, lane);
    if (idx + 16 < ntl)
      tile_critic((idx + 16) * 64, r2, true, rowcur, cx0, cx1, cx2, cx3,
                  wbuf, hw, obs, b1d, b2d, wv, bc3s, out, m, lg, msw, wm, cs, lane);
    if (idx + 32 < ntl)
      tile_critic((idx + 32) * 64, r2, false, rowcur, cx0, cx1, cx2, cx3,
                  wbuf, hw, obs, b1d, b2d, wv, bc3s, out, m, lg, msw, wm, cs, lane);
  }
}

extern "C" void kernel_launch(void* const* d_in, const int* in_sizes, int n_in,
                              void* d_out, int out_size, void* d_ws, size_t ws_size,
                              hipStream_t stream) {
  const float* obs = (const float*)d_in[0];
  const int* sid   = (const int*)d_in[1];
  const float* Wa1 = (const float*)d_in[2];
  const float* ba1 = (const float*)d_in[3];
  const float* Wa2 = (const float*)d_in[4];
  const float* ba2 = (const float*)d_in[5];
  const float* Wa3 = (const float*)d_in[6];
  const float* ba3 = (const float*)d_in[7];
  const float* Wc1 = (const float*)d_in[8];
  const float* bc1 = (const float*)d_in[9];
  const float* Wc2 = (const float*)d_in[10];
  const float* bc2 = (const float*)d_in[11];
  const float* Wc3 = (const float*)d_in[12];
  const float* bc3 = (const float*)d_in[13];
  float* out = (float*)d_out;
  char* ws = (char*)d_ws;

  int* cnt = (int*)(ws + CNT_OFF);
  unsigned short* perm = (unsigned short*)(ws + PERM_OFF);
  char* G = ws + WB_OFF;

  hipMemsetAsync(cnt, 0, St * sizeof(int), stream);
  k_fused<<<dim3(240), dim3(256), 0, stream>>>(sid, perm, cnt, Wa1, Wa2, Wa3, Wc1, Wc2, G);
  k_main<<<dim3(2, 16, 16), dim3(256), 0, stream>>>(
      obs, ba1, ba2, ba3, bc1, bc2, Wc3, bc3, cnt, perm, G, out);
}

// Round 16
// 24.064 us; speedup vs baseline: 1.1443x; 1.0923x over previous
//
#include <hip/hip_runtime.h>

#define Bt 32768
#define Dt 64
#define St 16
#define Ht 128
#define At 17

typedef __attribute__((ext_vector_type(8))) short bf16x8;
typedef __attribute__((ext_vector_type(4))) float f32x4;

__device__ __forceinline__ unsigned short f2bf(float f) {
  union { float f; unsigned u; } v; v.f = f;
  unsigned r = v.u + 0x7FFFu + ((v.u >> 16) & 1u);  // RNE
  return (unsigned short)(r >> 16);
}

// packed f32x2 -> bf16x2 in one VALU op (gfx950 v_cvt_pk_bf16_f32)
__device__ __forceinline__ unsigned cvtpk(float a, float b) {
  unsigned r;
  asm("v_cvt_pk_bf16_f32 %0, %1, %2" : "=v"(r) : "v"(a), "v"(b));
  return r;
}

// tanh(acc + bias) with b2 = 2*bias precomputed
__device__ __forceinline__ float tanh_fb(float acc, float b2) {
  const float t = __expf(__builtin_fmaf(acc, 2.0f, b2));  // inf-safe
  const float r = __builtin_amdgcn_rcpf(t + 1.0f);
  return __builtin_fmaf(-2.0f, r, 1.0f);
}

__device__ __forceinline__ f32x4 MFMA(bf16x8 a, bf16x8 b, f32x4 c) {
  return __builtin_amdgcn_mfma_f32_16x16x32_bf16(a, b, c, 0, 0, 0);
}

#define LGKM0() asm volatile("s_waitcnt lgkmcnt(0)" ::: "memory")

__device__ __forceinline__ bf16x8 wrd(const char* base, int srw, int n, int c,
                                      int lg, int msw) {
  return *(const bf16x8*)(base + n * srw + (((c) + lg * 16) ^ msw));
}

// store tanh(acc)+bias with b2 pre-doubled, in registers
__device__ __forceinline__ void storeh(char* hw, int msw, int lg, int t,
                                       const f32x4 acc, const f32x4 b2) {
  const unsigned lo = cvtpk(tanh_fb(acc[0], b2[0]), tanh_fb(acc[1], b2[1]));
  const unsigned hi = cvtpk(tanh_fb(acc[2], b2[2]), tanh_fb(acc[3], b2[3]));
  *(unsigned long long*)(hw + ((32 * t + 8 * lg) ^ msw)) =
      (unsigned long long)lo | ((unsigned long long)hi << 32);
}

// ---- one 64-row tile, actor role (biases in registers) ----
__device__ __forceinline__ void tile_actor(
    int tbase, int rnext, bool dopref, int& rowcur,
    f32x4& cx0, f32x4& cx1, f32x4& cx2, f32x4& cx3,
    const char* wbuf, char* hw, const float* obs,
    const f32x4 (&b1d)[8], const f32x4 (&b2d)[8], const f32x4 ba3v,
    const float ba316, float* out,
    int m, int lg, int msw, int wm, int cs) {
  union { bf16x8 v; unsigned u[4]; } XB0, XB1;
  XB0.u[0] = cvtpk(cx0[0], cx0[1]); XB0.u[1] = cvtpk(cx0[2], cx0[3]);
  XB0.u[2] = cvtpk(cx1[0], cx1[1]); XB0.u[3] = cvtpk(cx1[2], cx1[3]);
  XB1.u[0] = cvtpk(cx2[0], cx2[1]); XB1.u[1] = cvtpk(cx2[2], cx2[3]);
  XB1.u[2] = cvtpk(cx3[0], cx3[1]); XB1.u[3] = cvtpk(cx3[2], cx3[3]);
  const int myrow = rowcur;
  if (dopref) {  // next tile's obs: in flight across this tile's compute
    const float* ap = obs + rnext * Dt + lg * 8;
    cx0 = *(const f32x4*)(ap);      cx1 = *(const f32x4*)(ap + 4);
    cx2 = *(const f32x4*)(ap + 32); cx3 = *(const f32x4*)(ap + 36);
  }
  rowcur = rnext;
#pragma unroll
  for (int nt = 0; nt < 8; ++nt) {
    const bf16x8 a0 = wrd(wbuf, 128, nt * 16 + m, 0, lg, msw);
    const bf16x8 a1 = wrd(wbuf, 128, nt * 16 + m, 64, lg, msw);
    f32x4 acc = {0.f, 0.f, 0.f, 0.f};
    acc = MFMA(a0, XB0.v, acc);
    acc = MFMA(a1, XB1.v, acc);
    storeh(hw, msw, lg, nt, acc, b1d[nt]);
  }
  LGKM0();
  const bf16x8 h0 = *(const bf16x8*)(hw + ((0   + 16 * lg) ^ msw));
  const bf16x8 h1 = *(const bf16x8*)(hw + ((64  + 16 * lg) ^ msw));
  const bf16x8 h2 = *(const bf16x8*)(hw + ((128 + 16 * lg) ^ msw));
  const bf16x8 h3 = *(const bf16x8*)(hw + ((192 + 16 * lg) ^ msw));
#pragma unroll
  for (int nt = 0; nt < 8; ++nt) {
    const int n = nt * 16 + m;
    const bf16x8 w0 = wrd(wbuf + 16384, 256, n, 0, lg, msw);
    const bf16x8 w1 = wrd(wbuf + 16384, 256, n, 64, lg, msw);
    const bf16x8 w2 = wrd(wbuf + 16384, 256, n, 128, lg, msw);
    const bf16x8 w3 = wrd(wbuf + 16384, 256, n, 192, lg, msw);
    f32x4 acc = {0.f, 0.f, 0.f, 0.f};
    acc = MFMA(w0, h0, acc); acc = MFMA(w1, h1, acc);
    acc = MFMA(w2, h2, acc); acc = MFMA(w3, h3, acc);
    storeh(hw, msw, lg, nt, acc, b2d[nt]);
  }
  LGKM0();
  const bf16x8 H0 = *(const bf16x8*)(hw + ((0   + 16 * lg) ^ msw));
  const bf16x8 H1 = *(const bf16x8*)(hw + ((64  + 16 * lg) ^ msw));
  const bf16x8 H2 = *(const bf16x8*)(hw + ((128 + 16 * lg) ^ msw));
  const bf16x8 H3 = *(const bf16x8*)(hw + ((192 + 16 * lg) ^ msw));
  const char* W3 = wbuf + 49152;
  const bf16x8 e0 = wrd(W3, 256, m, 0, lg, msw);
  const bf16x8 e1 = wrd(W3, 256, m, 64, lg, msw);
  const bf16x8 e2 = wrd(W3, 256, m, 128, lg, msw);
  const bf16x8 e3 = wrd(W3, 256, m, 192, lg, msw);
  const bf16x8 f0 = wrd(W3, 256, 16 + m, 0, lg, msw);
  const bf16x8 f1 = wrd(W3, 256, 16 + m, 64, lg, msw);
  const bf16x8 f2 = wrd(W3, 256, 16 + m, 128, lg, msw);
  const bf16x8 f3 = wrd(W3, 256, 16 + m, 192, lg, msw);
  f32x4 p0 = {0.f, 0.f, 0.f, 0.f}, p1 = {0.f, 0.f, 0.f, 0.f};
  p0 = MFMA(e0, H0, p0); p0 = MFMA(e1, H1, p0);
  p0 = MFMA(e2, H2, p0); p0 = MFMA(e3, H3, p0);
  p1 = MFMA(f0, H0, p1); p1 = MFMA(f1, H1, p1);
  p1 = MFMA(f2, H2, p1); p1 = MFMA(f3, H3, p1);
  if (tbase + wm < cs) {
    float* orow = out + myrow * At;
#pragma unroll
    for (int i = 0; i < 4; ++i)                 // n = 4lg+i in 0..15
      orow[4 * lg + i] = p0[i] + ba3v[i];
    if (lg == 0) orow[16] = p1[0] + ba316;      // n = 16
  }
}

// ---- one 64-row tile, critic role (biases/Wc3 in registers) ----
__device__ __forceinline__ void tile_critic(
    int tbase, int rnext, bool dopref, int& rowcur,
    f32x4& cx0, f32x4& cx1, f32x4& cx2, f32x4& cx3,
    const char* wbuf, char* hw, const float* obs,
    const f32x4 (&b1d)[8], const f32x4 (&b2d)[8], const f32x4 (&wv)[8],
    const float bc3s, float* out,
    int m, int lg, int msw, int wm, int cs, int lane) {
  union { bf16x8 v; unsigned u[4]; } XB0, XB1;
  XB0.u[0] = cvtpk(cx0[0], cx0[1]); XB0.u[1] = cvtpk(cx0[2], cx0[3]);
  XB0.u[2] = cvtpk(cx1[0], cx1[1]); XB0.u[3] = cvtpk(cx1[2], cx1[3]);
  XB1.u[0] = cvtpk(cx2[0], cx2[1]); XB1.u[1] = cvtpk(cx2[2], cx2[3]);
  XB1.u[2] = cvtpk(cx3[0], cx3[1]); XB1.u[3] = cvtpk(cx3[2], cx3[3]);
  const int myrow = rowcur;
  if (dopref) {
    const float* ap = obs + rnext * Dt + lg * 8;
    cx0 = *(const f32x4*)(ap);      cx1 = *(const f32x4*)(ap + 4);
    cx2 = *(const f32x4*)(ap + 32); cx3 = *(const f32x4*)(ap + 36);
  }
  rowcur = rnext;
#pragma unroll
  for (int nt = 0; nt < 8; ++nt) {
    const bf16x8 a0 = wrd(wbuf, 128, nt * 16 + m, 0, lg, msw);
    const bf16x8 a1 = wrd(wbuf, 128, nt * 16 + m, 64, lg, msw);
    f32x4 acc = {0.f, 0.f, 0.f, 0.f};
    acc = MFMA(a0, XB0.v, acc);
    acc = MFMA(a1, XB1.v, acc);
    storeh(hw, msw, lg, nt, acc, b1d[nt]);
  }
  LGKM0();
  const bf16x8 h0 = *(const bf16x8*)(hw + ((0   + 16 * lg) ^ msw));
  const bf16x8 h1 = *(const bf16x8*)(hw + ((64  + 16 * lg) ^ msw));
  const bf16x8 h2 = *(const bf16x8*)(hw + ((128 + 16 * lg) ^ msw));
  const bf16x8 h3 = *(const bf16x8*)(hw + ((192 + 16 * lg) ^ msw));
  float vp = 0.f;
#pragma unroll
  for (int nt = 0; nt < 8; ++nt) {
    const int n = nt * 16 + m;
    const bf16x8 w0 = wrd(wbuf + 16384, 256, n, 0, lg, msw);
    const bf16x8 w1 = wrd(wbuf + 16384, 256, n, 64, lg, msw);
    const bf16x8 w2 = wrd(wbuf + 16384, 256, n, 128, lg, msw);
    const bf16x8 w3 = wrd(wbuf + 16384, 256, n, 192, lg, msw);
    f32x4 acc = {0.f, 0.f, 0.f, 0.f};
    acc = MFMA(w0, h0, acc); acc = MFMA(w1, h1, acc);
    acc = MFMA(w2, h2, acc); acc = MFMA(w3, h3, acc);
#pragma unroll
    for (int i = 0; i < 4; ++i)
      vp = __builtin_fmaf(tanh_fb(acc[i], b2d[nt][i]), wv[nt][i], vp);
  }
  vp += __shfl_xor(vp, 16);
  vp += __shfl_xor(vp, 32);
  if (lane < 16 && (tbase + wm < cs)) out[Bt * At + myrow] = vp + bc3s;
}

// ---------- SINGLE dispatch: in-block compact + fp32->LDS weight convert + MLP ----------
// block (role, s, idx): owns rows b in [idx*2048,(idx+1)*2048) with sid[b]==s.
// Partition is exact (each row in exactly one block per role); no workspace needed.
__global__ __launch_bounds__(256, 2) void k_all(
    const float* __restrict__ obs, const int* __restrict__ sid,
    const float* __restrict__ Wa1, const float* __restrict__ ba1,
    const float* __restrict__ Wa2, const float* __restrict__ ba2,
    const float* __restrict__ Wa3, const float* __restrict__ ba3,
    const float* __restrict__ Wc1, const float* __restrict__ bc1,
    const float* __restrict__ Wc2, const float* __restrict__ bc2,
    const float* __restrict__ Wc3, const float* __restrict__ bc3,
    float* __restrict__ out) {
  __shared__ __align__(16) char wbuf[57344];   // L1@0 16K | L2@16K 32K | L3@48K 8K
  __shared__ __align__(16) char hbuf[16384];   // 64 rows x 256B activations
  __shared__ unsigned short rlist[2048];       // compacted row ids (worst case)
  __shared__ int rcnt;

  const int tid = threadIdx.x;
  const int wave = tid >> 6, lane = tid & 63;
  const int m = lane & 15, lg = lane >> 4;
  const bool actor = (blockIdx.x == 0);
  const int s = blockIdx.y, idx = blockIdx.z;
  const int wm = wave * 16 + m;

  if (tid == 0) rcnt = 0;
  __syncthreads();

  // ---- ballot-compact rows of skill s from this block's sid slice ----
  const int ebase = idx * 2048;
#pragma unroll
  for (int r = 0; r < 8; ++r) {
    const int e = ebase + r * 256 + tid;
    const bool p = (sid[e] == s);
    const unsigned long long mk = __ballot(p);
    int wb = 0;
    if (lane == 0) wb = atomicAdd(&rcnt, (int)__popcll(mk));
    wb = __shfl(wb, 0);
    if (p) rlist[wb + (int)__popcll(mk & ((1ULL << lane) - 1ULL))] =
        (unsigned short)e;
  }
  __syncthreads();                       // rlist/rcnt ready
  const int cs = rcnt;
  const int cm1 = (cs > 0) ? cs - 1 : 0;
  const int ntl = (cs + 63) >> 6;

  // ---- tile-0 obs gather issued early (hides under weight conversion) ----
  f32x4 cx0 = {}, cx1 = {}, cx2 = {}, cx3 = {};
  int rowcur = 0;
  if (cs > 0) {
    rowcur = rlist[min(wm, cm1)];
    const float* ap = obs + rowcur * Dt + lg * 8;
    cx0 = *(const f32x4*)(ap);      cx1 = *(const f32x4*)(ap + 4);
    cx2 = *(const f32x4*)(ap + 32); cx3 = *(const f32x4*)(ap + 36);
  }

  // ---- convert this (role,s)'s fp32 weights -> bf16 [n][k] swizzled LDS image ----
  {
    const float* W1s = (actor ? Wa1 : Wc1) + s * Dt * Ht;  // [k=64][n=128]
    const float* W2s = (actor ? Wa2 : Wc2) + s * Ht * Ht;  // [k=128][n=128]
#pragma unroll
    for (int i = 0; i < 16; ++i) {     // L1 image: 4096 u32 (SRW=128)
      const int w = i * 256 + tid;
      const int n = w & 127, kp = w >> 7;
      const unsigned u =
          cvtpk(W1s[(2 * kp) * Ht + n], W1s[(2 * kp + 1) * Ht + n]);
      *(unsigned*)(wbuf + n * 128 + ((4 * kp) ^ ((n & 7) << 4))) = u;
    }
#pragma unroll
    for (int i = 0; i < 32; ++i) {     // L2 image: 8192 u32 (SRW=256)
      const int w = i * 256 + tid;
      const int n = w & 127, kp = w >> 7;
      const unsigned u =
          cvtpk(W2s[(2 * kp) * Ht + n], W2s[(2 * kp + 1) * Ht + n]);
      *(unsigned*)(wbuf + 16384 + n * 256 + ((4 * kp) ^ ((n & 7) << 4))) = u;
    }
    if (actor) {                       // L3 image: rows n<17 only (rest discarded)
      const float* W3s = Wa3 + s * Ht * At;
      for (int e = tid; e < Ht * At; e += 256) {
        const int k = e / At, n = e - k * At;
        *(unsigned short*)(wbuf + 49152 + n * 256 +
                           ((2 * k) ^ ((n & 7) << 4))) = f2bf(W3s[e]);
      }
    }
  }

  char* hw = hbuf + wm * 256;
  const int msw = (m & 7) << 4;

  if (actor) {
    // preload biases into registers (pre-doubled) BEFORE the barrier
    f32x4 b1d[8], b2d[8];
#pragma unroll
    for (int nt = 0; nt < 8; ++nt) {
      const f32x4 t1 = *(const f32x4*)(ba1 + s * Ht + nt * 16 + lg * 4);
      const f32x4 t2 = *(const f32x4*)(ba2 + s * Ht + nt * 16 + lg * 4);
      b1d[nt] = t1 + t1;
      b2d[nt] = t2 + t2;
    }
    const f32x4 ba3v = *(const f32x4*)(ba3 + s * At + 4 * lg);
    const float ba316 = ba3[s * At + 16];
    __syncthreads();                   // wbuf image + preloads complete
    for (int t = 0; t < ntl; ++t) {
      const int rn = rlist[min((t + 1) * 64 + wm, cm1)];
      tile_actor(t * 64, rn, t + 1 < ntl, rowcur, cx0, cx1, cx2, cx3,
                 wbuf, hw, obs, b1d, b2d, ba3v, ba316, out, m, lg, msw, wm, cs);
    }
  } else {
    f32x4 b1d[8], b2d[8], wv[8];
#pragma unroll
    for (int nt = 0; nt < 8; ++nt) {
      const f32x4 t1 = *(const f32x4*)(bc1 + s * Ht + nt * 16 + lg * 4);
      const f32x4 t2 = *(const f32x4*)(bc2 + s * Ht + nt * 16 + lg * 4);
      wv[nt] = *(const f32x4*)(Wc3 + s * Ht + nt * 16 + lg * 4);
      b1d[nt] = t1 + t1;
      b2d[nt] = t2 + t2;
    }
    const float bc3s = bc3[s];
    __syncthreads();
    for (int t = 0; t < ntl; ++t) {
      const int rn = rlist[min((t + 1) * 64 + wm, cm1)];
      tile_critic(t * 64, rn, t + 1 < ntl, rowcur, cx0, cx1, cx2, cx3,
                  wbuf, hw, obs, b1d, b2d, wv, bc3s, out, m, lg, msw, wm, cs,
                  lane);
    }
  }
}

extern "C" void kernel_launch(void* const* d_in, const int* in_sizes, int n_in,
                              void* d_out, int out_size, void* d_ws, size_t ws_size,
                              hipStream_t stream) {
  const float* obs = (const float*)d_in[0];
  const int* sid   = (const int*)d_in[1];
  const float* Wa1 = (const float*)d_in[2];
  const float* ba1 = (const float*)d_in[3];
  const float* Wa2 = (const float*)d_in[4];
  const float* ba2 = (const float*)d_in[5];
  const float* Wa3 = (const float*)d_in[6];
  const float* ba3 = (const float*)d_in[7];
  const float* Wc1 = (const float*)d_in[8];
  const float* bc1 = (const float*)d_in[9];
  const float* Wc2 = (const float*)d_in[10];
  const float* bc2 = (const float*)d_in[11];
  const float* Wc3 = (const float*)d_in[12];
  const float* bc3 = (const float*)d_in[13];
  float* out = (float*)d_out;

  k_all<<<dim3(2, 16, 16), dim3(256), 0, stream>>>(
      obs, sid, Wa1, ba1, Wa2, ba2, Wa3, ba3, Wc1, bc1, Wc2, bc2, Wc3, bc3,
      out);
}